// Round 11
// baseline (4070.727 us; speedup 1.0000x reference)
//
#include <hip/hip_runtime.h>

#define N_NODES 100000
#define N_EDGES 3200000
#define N_IN    128
#define N_OUT   64
#define ITERS   150
#define LEAK    0.01f

#define NBLK    512            // 2 blocks per CU -> 32 waves/CU
#define NT      1024           // 16 waves per block
#define GROUPS  256            // NT/4 quads; one row per quad (RPB <= GROUPS)
#define RPB     196            // ceil(100000/512) rows per block
#define SCAN_CHUNK 1024
#define SCAN_NBLK  98          // 98*1024 >= N_NODES+1
#define ARRSTR  16             // ints between arrival slots (64B)
#define YSTR    100096         // y buffer stride (float4-aligned)
#define NBUF    150

__device__ __forceinline__ float mml(float v) {
    v = (v < 0.0f) ? v * LEAK : v;
    if (v > 0.5f) v = 1.0f - 0.25f / v;
    return v;
}

__global__ void k_binit(const float* __restrict__ biases, float* __restrict__ b_in) {
    int i = blockIdx.x * blockDim.x + threadIdx.x;
    if (i < N_NODES) b_in[i] = biases[i];
}

// node_in.at[in_indices].set(in_w * x) -> last-write-wins for duplicates
__global__ void k_scatter_in(const float* __restrict__ x,
                             const float* __restrict__ in_w,
                             const int*   __restrict__ in_idx,
                             const float* __restrict__ biases,
                             float* __restrict__ b_in) {
    int k = threadIdx.x;
    if (k < N_IN) {
        int idx = in_idx[k];
        bool last = true;
        for (int j = k + 1; j < N_IN; ++j)
            if (in_idx[j] == idx) { last = false; break; }
        if (last) b_in[idx] = biases[idx] + in_w[k] * x[k];
    }
}

// y^(1) = act(0 + b_in)
__global__ void k_y0(const float* __restrict__ b_in, float* __restrict__ y0) {
    int i = blockIdx.x * blockDim.x + threadIdx.x;
    if (i < N_NODES) y0[i] = mml(b_in[i]);
}

// plain row histogram
__global__ void k_hist(const int* __restrict__ rows, int* __restrict__ counts) {
    int i = blockIdx.x * blockDim.x + threadIdx.x;
    int stride = gridDim.x * blockDim.x;
    for (; i < N_EDGES; i += stride) atomicAdd(&counts[rows[i]], 1);
}

__global__ void k_scan1(const int* __restrict__ counts, int* __restrict__ rp,
                        int* __restrict__ blockSums) {
    __shared__ int sm[SCAN_CHUNK];
    int t = threadIdx.x;
    int i = blockIdx.x * SCAN_CHUNK + t;
    int v = (i < N_NODES) ? counts[i] : 0;
    sm[t] = v;
    __syncthreads();
    for (int off = 1; off < SCAN_CHUNK; off <<= 1) {
        int add = (t >= off) ? sm[t - off] : 0;
        __syncthreads();
        sm[t] += add;
        __syncthreads();
    }
    if (i <= N_NODES) rp[i] = sm[t] - v;
    if (t == SCAN_CHUNK - 1) blockSums[blockIdx.x] = sm[t];
}

__global__ void k_scan2(int* __restrict__ blockSums) {
    __shared__ int sm[128];
    int t = threadIdx.x;
    int v = (t < SCAN_NBLK) ? blockSums[t] : 0;
    sm[t] = v;
    __syncthreads();
    for (int off = 1; off < 128; off <<= 1) {
        int add = (t >= off) ? sm[t - off] : 0;
        __syncthreads();
        sm[t] += add;
        __syncthreads();
    }
    if (t < SCAN_NBLK) blockSums[t] = sm[t] - v;
}

__global__ void k_scan3(int* __restrict__ rp, const int* __restrict__ blockSums,
                        int* __restrict__ next) {
    int i = blockIdx.x * SCAN_CHUNK + threadIdx.x;
    if (i <= N_NODES) {
        int val = rp[i] + blockSums[blockIdx.x];
        rp[i] = val;
        if (i < N_NODES) next[i] = val;
    }
}

// row-major CSR fill: (col, weight) int2
__global__ void k_scatter_edges(const int* __restrict__ rows, const int* __restrict__ cols,
                                const float* __restrict__ w,
                                int* __restrict__ next, int2* __restrict__ csr) {
    int i = blockIdx.x * blockDim.x + threadIdx.x;
    int stride = gridDim.x * blockDim.x;
    for (; i < N_EDGES; i += stride) {
        int r = rows[i];
        int p = atomicAdd(&next[r], 1);
        csr[p] = make_int2(cols[i], __float_as_int(w[i]));
    }
}

template <bool SC1>
__device__ __forceinline__ float row_part(const int2* __restrict__ csr,
                                          const float* __restrict__ ysrc,
                                          int e, const int end) {
    float a0 = 0.f, a1 = 0.f;
    for (; e + 4 < end; e += 8) {          // lane-strided, 2-way MLP per row
        const int2 c0 = csr[e];
        const int2 c1 = csr[e + 4];
        float y0, y1;
        if (SC1) {
            y0 = __hip_atomic_load(&ysrc[c0.x], __ATOMIC_RELAXED, __HIP_MEMORY_SCOPE_AGENT);
            y1 = __hip_atomic_load(&ysrc[c1.x], __ATOMIC_RELAXED, __HIP_MEMORY_SCOPE_AGENT);
        } else { y0 = ysrc[c0.x]; y1 = ysrc[c1.x]; }
        a0 = fmaf(__int_as_float(c0.y), y0, a0);
        a1 = fmaf(__int_as_float(c1.y), y1, a1);
    }
    if (e < end) {
        const int2 c = csr[e];
        const float yv = SC1 ? __hip_atomic_load(&ysrc[c.x], __ATOMIC_RELAXED,
                                                 __HIP_MEMORY_SCOPE_AGENT)
                             : ysrc[c.x];
        a0 = fmaf(__int_as_float(c.y), yv, a0);
    }
    return a0 + a1;
}

// R9 structure at 2 blocks/CU (32 waves/CU): latency-vs-bandwidth A/B.
// One row per quad; everything else identical to round 9's winner.
template <bool SC1>
__global__ __launch_bounds__(NT, 8) void k_iterate(
    const int*  __restrict__ rp,
    const int2* __restrict__ csr,
    const float* __restrict__ b_in,
    float* __restrict__ ybufs,
    int* __restrict__ arr,
    const int* __restrict__ out_idx,
    const float* __restrict__ out_w,
    float* __restrict__ out,
    int nbuf)
{
    const int b = blockIdx.x, t = threadIdx.x;
    const int gq = t >> 2, j = t & 3;
    const int row0 = b * RPB;
    const int row_end = (row0 + RPB < N_NODES) ? row0 + RPB : N_NODES;
    const int nrows = row_end - row0;
    const int r1 = row0 + gq;
    const bool h1 = (gq < nrows);

    // iteration-invariant per-thread row state (registers)
    int beg1 = 0, end1 = 0;
    float bi1 = 0.f;
    if (h1) { beg1 = rp[r1] + j; end1 = rp[r1 + 1]; bi1 = b_in[r1]; }

    for (int it = 1; it <= ITERS - 1; ++it) {
        const float* ysrc = ybufs + (size_t)((it - 1) % nbuf) * YSTR;
        float*       ydst = ybufs + (size_t)(it % nbuf) * YSTR;

        float acc1 = h1 ? row_part<SC1>(csr, ysrc, beg1, end1) : 0.f;

        acc1 += __shfl_xor(acc1, 1); acc1 += __shfl_xor(acc1, 2);
        if (j == 0 && h1)
            __hip_atomic_store(&ydst[r1], mml(bi1 + acc1),
                               __ATOMIC_RELAXED, __HIP_MEMORY_SCOPE_AGENT);

        asm volatile("s_waitcnt vmcnt(0)" ::: "memory");  // y stores ack'd at MALL
        __builtin_amdgcn_s_barrier();                     // all waves drained
        if (t == 0)
            __hip_atomic_store(&arr[b * ARRSTR], it, __ATOMIC_RELAXED,
                               __HIP_MEMORY_SCOPE_AGENT);
        if (t < NBLK) {
            while (__hip_atomic_load(&arr[t * ARRSTR], __ATOMIC_RELAXED,
                                     __HIP_MEMORY_SCOPE_AGENT) < it)
                __builtin_amdgcn_s_sleep(1);
        }
        __syncthreads();
    }

    if (b == 0 && t < N_OUT) {
        const float* yfin = ybufs + (size_t)((ITERS - 1) % nbuf) * YSTR;
        out[t] = out_w[t] * __hip_atomic_load(&yfin[out_idx[t]],
                   __ATOMIC_RELAXED, __HIP_MEMORY_SCOPE_AGENT);
    }
}

extern "C" void kernel_launch(void* const* d_in, const int* in_sizes, int n_in,
                              void* d_out, int out_size, void* d_ws, size_t ws_size,
                              hipStream_t stream) {
    const float* x      = (const float*)d_in[0];
    const float* in_w   = (const float*)d_in[1];
    const float* rec_w  = (const float*)d_in[2];
    const float* biases = (const float*)d_in[3];
    const float* out_w  = (const float*)d_in[4];
    const int*   in_idx = (const int*)d_in[5];
    const int*   e_rows = (const int*)d_in[6];
    const int*   e_cols = (const int*)d_in[7];
    const int*   out_idx= (const int*)d_in[8];
    float* out = (float*)d_out;

    char* ws = (char*)d_ws;
    float* b_in    = (float*)ws;                       // 100000 f
    int*   rp      = (int*)(b_in + N_NODES);           // 100001 (+pad)
    int*   counts  = rp + (N_NODES + 64);              // 100000 (also `next`)
    int*   blockSums = counts + N_NODES;               // 128
    int*   arr     = blockSums + 128;                  // NBLK*ARRSTR
    size_t off = (size_t)((char*)(arr + NBLK * ARRSTR) - ws);
    off = (off + 255) & ~(size_t)255;
    int2* csr = (int2*)(ws + off);                     // 25.6 MB (L2-resident slabs)
    size_t off2 = off + (size_t)N_EDGES * sizeof(int2);
    off2 = (off2 + 255) & ~(size_t)255;
    float* ybufs = (float*)(ws + off2);

    long long avail = ((long long)ws_size - (long long)off2) /
                      (long long)(YSTR * sizeof(float));
    int nbuf, sc1mode;
    if (avail >= NBUF) { nbuf = NBUF; sc1mode = 0; }   // cold-L2 invariant
    else               { nbuf = 2;    sc1mode = 1; }   // sc1 gathers

    hipMemsetAsync(counts, 0, N_NODES * sizeof(int), stream);
    hipMemsetAsync(arr, 0, NBLK * ARRSTR * sizeof(int), stream);

    k_binit<<<391, 256, 0, stream>>>(biases, b_in);
    k_scatter_in<<<1, 128, 0, stream>>>(x, in_w, in_idx, biases, b_in);
    k_y0<<<391, 256, 0, stream>>>(b_in, ybufs);        // buffer 0 = y^(1)

    k_hist<<<1024, 256, 0, stream>>>(e_rows, counts);
    k_scan1<<<SCAN_NBLK, SCAN_CHUNK, 0, stream>>>(counts, rp, blockSums);
    k_scan2<<<1, 128, 0, stream>>>(blockSums);
    k_scan3<<<SCAN_NBLK, SCAN_CHUNK, 0, stream>>>(rp, blockSums, counts);
    k_scatter_edges<<<1024, 256, 0, stream>>>(e_rows, e_cols, rec_w, counts, csr);

    int*   rp_a   = rp;
    int2*  csr_a  = csr;
    float* bin_a  = b_in;
    float* yb_a   = ybufs;
    int*   arr_a  = arr;
    const int*   oidx_a = out_idx;
    const float* ow_a   = out_w;
    float* out_a  = out;
    void* args[] = { &rp_a, &csr_a, &bin_a, &yb_a, &arr_a,
                     &oidx_a, &ow_a, &out_a, &nbuf };
    void* kfn = sc1mode ? (void*)k_iterate<true> : (void*)k_iterate<false>;
    hipLaunchCooperativeKernel(kfn, dim3(NBLK), dim3(NT), args, 0, stream);
}

// Round 12
// 3106.053 us; speedup vs baseline: 1.3106x; 1.3106x over previous
//
#include <hip/hip_runtime.h>

#define N_NODES 100000
#define N_EDGES 3200000
#define N_IN    128
#define N_OUT   64
#define ITERS   150
#define LEAK    0.01f

#define NBLK    256            // 1 block per CU
#define NT      960            // 15 waves
#define GROUPS  240            // NT/4 quads
#define RPB     391            // ceil(100000/256) rows per block
#define SCAN_CHUNK 1024
#define SCAN_NBLK  98          // 98*1024 >= N_NODES+1
#define ARRSTR  16             // ints between arrival slots (64B)
#define YSTR    100096         // y buffer stride (float4-aligned)
#define NBUF    150

__device__ __forceinline__ float mml(float v) {
    v = (v < 0.0f) ? v * LEAK : v;
    if (v > 0.5f) v = 1.0f - 0.25f / v;
    return v;
}

__global__ void k_binit(const float* __restrict__ biases, float* __restrict__ b_in) {
    int i = blockIdx.x * blockDim.x + threadIdx.x;
    if (i < N_NODES) b_in[i] = biases[i];
}

// node_in.at[in_indices].set(in_w * x) -> last-write-wins for duplicates
__global__ void k_scatter_in(const float* __restrict__ x,
                             const float* __restrict__ in_w,
                             const int*   __restrict__ in_idx,
                             const float* __restrict__ biases,
                             float* __restrict__ b_in) {
    int k = threadIdx.x;
    if (k < N_IN) {
        int idx = in_idx[k];
        bool last = true;
        for (int j = k + 1; j < N_IN; ++j)
            if (in_idx[j] == idx) { last = false; break; }
        if (last) b_in[idx] = biases[idx] + in_w[k] * x[k];
    }
}

// y^(1) = act(0 + b_in)
__global__ void k_y0(const float* __restrict__ b_in, float* __restrict__ y0) {
    int i = blockIdx.x * blockDim.x + threadIdx.x;
    if (i < N_NODES) y0[i] = mml(b_in[i]);
}

// plain row histogram
__global__ void k_hist(const int* __restrict__ rows, int* __restrict__ counts) {
    int i = blockIdx.x * blockDim.x + threadIdx.x;
    int stride = gridDim.x * blockDim.x;
    for (; i < N_EDGES; i += stride) atomicAdd(&counts[rows[i]], 1);
}

__global__ void k_scan1(const int* __restrict__ counts, int* __restrict__ rp,
                        int* __restrict__ blockSums) {
    __shared__ int sm[SCAN_CHUNK];
    int t = threadIdx.x;
    int i = blockIdx.x * SCAN_CHUNK + t;
    int v = (i < N_NODES) ? counts[i] : 0;
    sm[t] = v;
    __syncthreads();
    for (int off = 1; off < SCAN_CHUNK; off <<= 1) {
        int add = (t >= off) ? sm[t - off] : 0;
        __syncthreads();
        sm[t] += add;
        __syncthreads();
    }
    if (i <= N_NODES) rp[i] = sm[t] - v;
    if (t == SCAN_CHUNK - 1) blockSums[blockIdx.x] = sm[t];
}

__global__ void k_scan2(int* __restrict__ blockSums) {
    __shared__ int sm[128];
    int t = threadIdx.x;
    int v = (t < SCAN_NBLK) ? blockSums[t] : 0;
    sm[t] = v;
    __syncthreads();
    for (int off = 1; off < 128; off <<= 1) {
        int add = (t >= off) ? sm[t - off] : 0;
        __syncthreads();
        sm[t] += add;
        __syncthreads();
    }
    if (t < SCAN_NBLK) blockSums[t] = sm[t] - v;
}

__global__ void k_scan3(int* __restrict__ rp, const int* __restrict__ blockSums,
                        int* __restrict__ next) {
    int i = blockIdx.x * SCAN_CHUNK + threadIdx.x;
    if (i <= N_NODES) {
        int val = rp[i] + blockSums[blockIdx.x];
        rp[i] = val;
        if (i < N_NODES) next[i] = val;
    }
}

// row-major CSR fill: (col, weight) int2
__global__ void k_scatter_edges(const int* __restrict__ rows, const int* __restrict__ cols,
                                const float* __restrict__ w,
                                int* __restrict__ next, int2* __restrict__ csr) {
    int i = blockIdx.x * blockDim.x + threadIdx.x;
    int stride = gridDim.x * blockDim.x;
    for (; i < N_EDGES; i += stride) {
        int r = rows[i];
        int p = atomicAdd(&next[r], 1);
        csr[p] = make_int2(cols[i], __float_as_int(w[i]));
    }
}

// 4-deep clamped MLP: four independent csr-load->gather chains per trip.
// Clamped index min(e+4k, end-1) always reads a REAL edge of this row
// (in-bounds), and the weight is zeroed via select when e+4k >= end.
// No padding -> CSR stays 25.6MB (L2-resident slabs). No divergence.
template <bool SC1>
__device__ __forceinline__ float row_part(const int2* __restrict__ csr,
                                          const float* __restrict__ ysrc,
                                          int e, const int end) {
    float a0 = 0.f, a1 = 0.f, a2 = 0.f, a3 = 0.f;
    const int last = end - 1;
    while (e < end) {
        const int e1 = e + 4, e2 = e + 8, e3 = e + 12;
        const int2 c0 = csr[e];
        const int2 c1 = csr[(e1 < last) ? e1 : last];
        const int2 c2 = csr[(e2 < last) ? e2 : last];
        const int2 c3 = csr[(e3 < last) ? e3 : last];
        const float w0 = __int_as_float(c0.y);
        const float w1 = (e1 < end) ? __int_as_float(c1.y) : 0.f;
        const float w2 = (e2 < end) ? __int_as_float(c2.y) : 0.f;
        const float w3 = (e3 < end) ? __int_as_float(c3.y) : 0.f;
        float y0, y1, y2, y3;
        if (SC1) {
            y0 = __hip_atomic_load(&ysrc[c0.x], __ATOMIC_RELAXED, __HIP_MEMORY_SCOPE_AGENT);
            y1 = __hip_atomic_load(&ysrc[c1.x], __ATOMIC_RELAXED, __HIP_MEMORY_SCOPE_AGENT);
            y2 = __hip_atomic_load(&ysrc[c2.x], __ATOMIC_RELAXED, __HIP_MEMORY_SCOPE_AGENT);
            y3 = __hip_atomic_load(&ysrc[c3.x], __ATOMIC_RELAXED, __HIP_MEMORY_SCOPE_AGENT);
        } else {
            y0 = ysrc[c0.x]; y1 = ysrc[c1.x]; y2 = ysrc[c2.x]; y3 = ysrc[c3.x];
        }
        a0 = fmaf(w0, y0, a0);
        a1 = fmaf(w1, y1, a1);
        a2 = fmaf(w2, y2, a2);
        a3 = fmaf(w3, y3, a3);
        e += 16;
    }
    return (a0 + a1) + (a2 + a3);
}

// R9 winner geometry + 4-deep MLP row_part. Everything else unchanged:
// relaxed arrival store (no wbl2), own-slot polling, rotating cold buffers.
template <bool SC1>
__global__ __launch_bounds__(NT) void k_iterate(
    const int*  __restrict__ rp,
    const int2* __restrict__ csr,
    const float* __restrict__ b_in,
    float* __restrict__ ybufs,
    int* __restrict__ arr,
    const int* __restrict__ out_idx,
    const float* __restrict__ out_w,
    float* __restrict__ out,
    int nbuf)
{
    const int b = blockIdx.x, t = threadIdx.x;
    const int gq = t >> 2, j = t & 3;
    const int row0 = b * RPB;
    const int row_end = (row0 + RPB < N_NODES) ? row0 + RPB : N_NODES;
    const int nrows = row_end - row0;
    const int r1 = row0 + gq, r2 = row0 + gq + GROUPS;
    const bool h1 = (gq < nrows), h2 = (gq + GROUPS < nrows);

    // iteration-invariant per-thread row state (registers)
    int beg1 = 0, end1 = 0, beg2 = 0, end2 = 0;
    float bi1 = 0.f, bi2 = 0.f;
    if (h1) { beg1 = rp[r1] + j; end1 = rp[r1 + 1]; bi1 = b_in[r1]; }
    if (h2) { beg2 = rp[r2] + j; end2 = rp[r2 + 1]; bi2 = b_in[r2]; }

    for (int it = 1; it <= ITERS - 1; ++it) {
        const float* ysrc = ybufs + (size_t)((it - 1) % nbuf) * YSTR;
        float*       ydst = ybufs + (size_t)(it % nbuf) * YSTR;

        float acc1 = h1 ? row_part<SC1>(csr, ysrc, beg1, end1) : 0.f;
        float acc2 = h2 ? row_part<SC1>(csr, ysrc, beg2, end2) : 0.f;

        acc1 += __shfl_xor(acc1, 1); acc1 += __shfl_xor(acc1, 2);
        acc2 += __shfl_xor(acc2, 1); acc2 += __shfl_xor(acc2, 2);
        if (j == 0) {
            if (h1)
                __hip_atomic_store(&ydst[r1], mml(bi1 + acc1),
                                   __ATOMIC_RELAXED, __HIP_MEMORY_SCOPE_AGENT);
            if (h2)
                __hip_atomic_store(&ydst[r2], mml(bi2 + acc2),
                                   __ATOMIC_RELAXED, __HIP_MEMORY_SCOPE_AGENT);
        }
        asm volatile("s_waitcnt vmcnt(0)" ::: "memory");  // y stores ack'd at MALL
        __builtin_amdgcn_s_barrier();                     // all waves drained
        if (t == 0)
            __hip_atomic_store(&arr[b * ARRSTR], it, __ATOMIC_RELAXED,
                               __HIP_MEMORY_SCOPE_AGENT);
        if (t < NBLK) {
            while (__hip_atomic_load(&arr[t * ARRSTR], __ATOMIC_RELAXED,
                                     __HIP_MEMORY_SCOPE_AGENT) < it)
                __builtin_amdgcn_s_sleep(1);
        }
        __syncthreads();
    }

    if (b == 0 && t < N_OUT) {
        const float* yfin = ybufs + (size_t)((ITERS - 1) % nbuf) * YSTR;
        out[t] = out_w[t] * __hip_atomic_load(&yfin[out_idx[t]],
                   __ATOMIC_RELAXED, __HIP_MEMORY_SCOPE_AGENT);
    }
}

extern "C" void kernel_launch(void* const* d_in, const int* in_sizes, int n_in,
                              void* d_out, int out_size, void* d_ws, size_t ws_size,
                              hipStream_t stream) {
    const float* x      = (const float*)d_in[0];
    const float* in_w   = (const float*)d_in[1];
    const float* rec_w  = (const float*)d_in[2];
    const float* biases = (const float*)d_in[3];
    const float* out_w  = (const float*)d_in[4];
    const int*   in_idx = (const int*)d_in[5];
    const int*   e_rows = (const int*)d_in[6];
    const int*   e_cols = (const int*)d_in[7];
    const int*   out_idx= (const int*)d_in[8];
    float* out = (float*)d_out;

    char* ws = (char*)d_ws;
    float* b_in    = (float*)ws;                       // 100000 f
    int*   rp      = (int*)(b_in + N_NODES);           // 100001 (+pad)
    int*   counts  = rp + (N_NODES + 64);              // 100000 (also `next`)
    int*   blockSums = counts + N_NODES;               // 128
    int*   arr     = blockSums + 128;                  // NBLK*ARRSTR
    size_t off = (size_t)((char*)(arr + NBLK * ARRSTR) - ws);
    off = (off + 255) & ~(size_t)255;
    int2* csr = (int2*)(ws + off);                     // 25.6 MB (L2-resident slabs)
    size_t off2 = off + (size_t)N_EDGES * sizeof(int2);
    off2 = (off2 + 255) & ~(size_t)255;
    float* ybufs = (float*)(ws + off2);

    long long avail = ((long long)ws_size - (long long)off2) /
                      (long long)(YSTR * sizeof(float));
    int nbuf, sc1mode;
    if (avail >= NBUF) { nbuf = NBUF; sc1mode = 0; }   // cold-L2 invariant
    else               { nbuf = 2;    sc1mode = 1; }   // sc1 gathers

    hipMemsetAsync(counts, 0, N_NODES * sizeof(int), stream);
    hipMemsetAsync(arr, 0, NBLK * ARRSTR * sizeof(int), stream);

    k_binit<<<391, 256, 0, stream>>>(biases, b_in);
    k_scatter_in<<<1, 128, 0, stream>>>(x, in_w, in_idx, biases, b_in);
    k_y0<<<391, 256, 0, stream>>>(b_in, ybufs);        // buffer 0 = y^(1)

    k_hist<<<1024, 256, 0, stream>>>(e_rows, counts);
    k_scan1<<<SCAN_NBLK, SCAN_CHUNK, 0, stream>>>(counts, rp, blockSums);
    k_scan2<<<1, 128, 0, stream>>>(blockSums);
    k_scan3<<<SCAN_NBLK, SCAN_CHUNK, 0, stream>>>(rp, blockSums, counts);
    k_scatter_edges<<<1024, 256, 0, stream>>>(e_rows, e_cols, rec_w, counts, csr);

    int*   rp_a   = rp;
    int2*  csr_a  = csr;
    float* bin_a  = b_in;
    float* yb_a   = ybufs;
    int*   arr_a  = arr;
    const int*   oidx_a = out_idx;
    const float* ow_a   = out_w;
    float* out_a  = out;
    void* args[] = { &rp_a, &csr_a, &bin_a, &yb_a, &arr_a,
                     &oidx_a, &ow_a, &out_a, &nbuf };
    void* kfn = sc1mode ? (void*)k_iterate<true> : (void*)k_iterate<false>;
    hipLaunchCooperativeKernel(kfn, dim3(NBLK), dim3(NT), args, 0, stream);
}